// Round 1
// baseline (4232.113 us; speedup 1.0000x reference)
//
#include <hip/hip_runtime.h>
#include <hip/hip_bf16.h>
#include <math.h>

#define TOPK 2

// ---------------------------------------------------------------- router ---
// One wave (64 lanes) per token. Computes logits = x@Wg+bg, noise_logits =
// x@Wn+bn, noisy = logits + noise*softplus(noise_logits), top-2 + softmax
// gate over the two selected experts. Also counts tokens per expert.
template<int E>
__global__ __launch_bounds__(64) void router_kernel(
    const float* __restrict__ x, const float* __restrict__ noise,
    const float* __restrict__ Wg, const float* __restrict__ bg,
    const float* __restrict__ Wn, const float* __restrict__ bn,
    int T, int D,
    int* __restrict__ count, int* __restrict__ topk_e, float* __restrict__ topk_g)
{
    int t = blockIdx.x;
    int lane = threadIdx.x;
    float ag[E], an[E];
#pragma unroll
    for (int e = 0; e < E; ++e) { ag[e] = 0.f; an[e] = 0.f; }
    const float* xrow = x + (size_t)t * D;
    for (int d = lane; d < D; d += 64) {
        float xv = xrow[d];
        const float* wgr = Wg + (size_t)d * E;
        const float* wnr = Wn + (size_t)d * E;
#pragma unroll
        for (int e = 0; e < E; ++e) {
            ag[e] = fmaf(xv, wgr[e], ag[e]);
            an[e] = fmaf(xv, wnr[e], an[e]);
        }
    }
#pragma unroll
    for (int e = 0; e < E; ++e) {
#pragma unroll
        for (int off = 32; off; off >>= 1) {
            ag[e] += __shfl_xor(ag[e], off, 64);
            an[e] += __shfl_xor(an[e], off, 64);
        }
    }
    if (lane == 0) {
        float noisy[E];
#pragma unroll
        for (int e = 0; e < E; ++e) {
            float lg = ag[e] + bg[e];
            float nl = an[e] + bn[e];
            // stable softplus: max(x,0) + log1p(exp(-|x|))
            float sp = fmaxf(nl, 0.f) + log1pf(expf(-fabsf(nl)));
            noisy[e] = lg + noise[(size_t)t * E + e] * sp;
        }
        int e0 = 0; float v0 = noisy[0];
#pragma unroll
        for (int e = 1; e < E; ++e) if (noisy[e] > v0) { v0 = noisy[e]; e0 = e; }
        int e1 = -1; float v1 = -INFINITY;
#pragma unroll
        for (int e = 0; e < E; ++e) if (e != e0 && noisy[e] > v1) { v1 = noisy[e]; e1 = e; }
        // softmax over the two selected logits (others are -inf -> 0)
        float d1 = expf(v1 - v0);
        float g0 = 1.f / (1.f + d1);
        float g1 = d1 / (1.f + d1);
        topk_e[2 * t] = e0; topk_e[2 * t + 1] = e1;
        topk_g[2 * t] = g0; topk_g[2 * t + 1] = g1;
        atomicAdd(&count[e0], 1);
        atomicAdd(&count[e1], 1);
    }
}

// ------------------------------------------------------------------ scan ---
__global__ void scan_kernel(const int* __restrict__ count, int* __restrict__ offsets, int E)
{
    if (threadIdx.x == 0 && blockIdx.x == 0) {
        int acc = 0;
        for (int e = 0; e < E; ++e) { offsets[e] = acc; acc += count[e]; }
        offsets[E] = acc;
    }
}

// --------------------------------------------------------------- scatter ---
__global__ void scatter_kernel(
    const int* __restrict__ topk_e, const float* __restrict__ topk_g,
    const int* __restrict__ offsets, int* __restrict__ fill,
    int* __restrict__ rows, float* __restrict__ rgate, int T)
{
    int t = blockIdx.x * blockDim.x + threadIdx.x;
    if (t >= T) return;
#pragma unroll
    for (int k = 0; k < TOPK; ++k) {
        int e = topk_e[2 * t + k];
        int slot = atomicAdd(&fill[e], 1);
        int p = offsets[e] + slot;
        rows[p] = t;
        rgate[p] = topk_g[2 * t + k];
    }
}

// ---------------------------------------------------------------- GEMM 1 ---
// hbuf[base+m][n] = relu( sum_d x[rows[base+m]][d] * W1[e][d][n0g+n] + b1[e][n0g+n] )
// 64x64 tile, 256 threads, 4x4 per thread, K-step 16.
__global__ __launch_bounds__(256) void gemm1_kernel(
    const float* __restrict__ x,
    const float* __restrict__ W1, const float* __restrict__ b1,
    const int* __restrict__ count, const int* __restrict__ offsets,
    const int* __restrict__ rows,
    float* __restrict__ hbuf,
    int D, int H, int Hc, int hc0)
{
    int e = blockIdx.z;
    int cnt = count[e];
    int m0 = blockIdx.y * 64;
    if (m0 >= cnt) return;
    int base = offsets[e];
    int n0l = blockIdx.x * 64;     // column within chunk
    int n0g = hc0 + n0l;           // global H column

    __shared__ float As[16][64];
    __shared__ float Bs[16][64];

    int tx = threadIdx.x & 15;
    int ty = threadIdx.x >> 4;

    // A-load indices
    int am  = threadIdx.x >> 2;          // 0..63
    int akq = (threadIdx.x & 3) * 4;     // 0,4,8,12
    int ar  = rows[base + min(m0 + am, cnt - 1)];
    const float* aptr = x + (size_t)ar * D + akq;
    // B-load indices
    int bk = threadIdx.x >> 4;           // 0..15
    int bn = (threadIdx.x & 15) * 4;     // 0..60
    const float* bptr = W1 + ((size_t)e * D + bk) * H + n0g + bn;

    float acc[4][4] = {};
    for (int k0 = 0; k0 < D; k0 += 16) {
        float4 av = *(const float4*)(aptr + k0);
        float4 bv = *(const float4*)(bptr + (size_t)k0 * H);
        As[akq + 0][am] = av.x; As[akq + 1][am] = av.y;
        As[akq + 2][am] = av.z; As[akq + 3][am] = av.w;
        *(float4*)&Bs[bk][bn] = bv;
        __syncthreads();
#pragma unroll
        for (int k = 0; k < 16; ++k) {
            float a[4], b[4];
#pragma unroll
            for (int i = 0; i < 4; ++i) a[i] = As[k][ty * 4 + i];
#pragma unroll
            for (int j = 0; j < 4; ++j) b[j] = Bs[k][tx * 4 + j];
#pragma unroll
            for (int i = 0; i < 4; ++i)
#pragma unroll
                for (int j = 0; j < 4; ++j)
                    acc[i][j] = fmaf(a[i], b[j], acc[i][j]);
        }
        __syncthreads();
    }
    float4 bias = *(const float4*)(b1 + (size_t)e * H + n0g + tx * 4);
#pragma unroll
    for (int i = 0; i < 4; ++i) {
        int m = m0 + ty * 4 + i;
        if (m < cnt) {
            float4 v;
            v.x = fmaxf(acc[i][0] + bias.x, 0.f);
            v.y = fmaxf(acc[i][1] + bias.y, 0.f);
            v.z = fmaxf(acc[i][2] + bias.z, 0.f);
            v.w = fmaxf(acc[i][3] + bias.w, 0.f);
            *(float4*)(hbuf + (size_t)(base + m) * Hc + n0l + tx * 4) = v;
        }
    }
}

// ---------------------------------------------------------------- GEMM 2 ---
// out[rows[base+m]][n] += gate * ( sum_k hbuf[base+m][k] * W2[e][hc0+k][n] (+ b2[e][n] on first chunk) )
__global__ __launch_bounds__(256) void gemm2_kernel(
    const float* __restrict__ hbuf,
    const float* __restrict__ W2, const float* __restrict__ b2,
    const int* __restrict__ count, const int* __restrict__ offsets,
    const int* __restrict__ rows, const float* __restrict__ rgate,
    float* __restrict__ out,
    int D, int H, int Hc, int hc0, int addb2)
{
    int e = blockIdx.z;
    int cnt = count[e];
    int m0 = blockIdx.y * 64;
    if (m0 >= cnt) return;
    int base = offsets[e];
    int n0 = blockIdx.x * 64;

    __shared__ float As[16][64];
    __shared__ float Bs[16][64];

    int tx = threadIdx.x & 15;
    int ty = threadIdx.x >> 4;

    int am  = threadIdx.x >> 2;
    int akq = (threadIdx.x & 3) * 4;
    int amc = min(m0 + am, cnt - 1);
    const float* aptr = hbuf + (size_t)(base + amc) * Hc + akq;
    int bk = threadIdx.x >> 4;
    int bn = (threadIdx.x & 15) * 4;
    const float* bptr = W2 + ((size_t)e * H + hc0 + bk) * D + n0 + bn;

    float acc[4][4] = {};
    for (int k0 = 0; k0 < Hc; k0 += 16) {
        float4 av = *(const float4*)(aptr + k0);
        float4 bv = *(const float4*)(bptr + (size_t)k0 * D);
        As[akq + 0][am] = av.x; As[akq + 1][am] = av.y;
        As[akq + 2][am] = av.z; As[akq + 3][am] = av.w;
        *(float4*)&Bs[bk][bn] = bv;
        __syncthreads();
#pragma unroll
        for (int k = 0; k < 16; ++k) {
            float a[4], b[4];
#pragma unroll
            for (int i = 0; i < 4; ++i) a[i] = As[k][ty * 4 + i];
#pragma unroll
            for (int j = 0; j < 4; ++j) b[j] = Bs[k][tx * 4 + j];
#pragma unroll
            for (int i = 0; i < 4; ++i)
#pragma unroll
                for (int j = 0; j < 4; ++j)
                    acc[i][j] = fmaf(a[i], b[j], acc[i][j]);
        }
        __syncthreads();
    }
    float4 bias = make_float4(0.f, 0.f, 0.f, 0.f);
    if (addb2) bias = *(const float4*)(b2 + (size_t)e * D + n0 + tx * 4);
#pragma unroll
    for (int i = 0; i < 4; ++i) {
        int m = m0 + ty * 4 + i;
        if (m < cnt) {
            int t = rows[base + m];
            float g = rgate[base + m];
            float* op = out + (size_t)t * D + n0 + tx * 4;
            atomicAdd(op + 0, g * (acc[i][0] + bias.x));
            atomicAdd(op + 1, g * (acc[i][1] + bias.y));
            atomicAdd(op + 2, g * (acc[i][2] + bias.z));
            atomicAdd(op + 3, g * (acc[i][3] + bias.w));
        }
    }
}

// ------------------------------------------------------------------ host ---
extern "C" void kernel_launch(void* const* d_in, const int* in_sizes, int n_in,
                              void* d_out, int out_size, void* d_ws, size_t ws_size,
                              hipStream_t stream)
{
    const float* x     = (const float*)d_in[0];
    const float* noise = (const float*)d_in[1];
    const float* Wg    = (const float*)d_in[2];
    const float* bg    = (const float*)d_in[3];
    const float* Wn    = (const float*)d_in[4];
    const float* bn    = (const float*)d_in[5];
    const float* W1    = (const float*)d_in[6];
    const float* b1    = (const float*)d_in[7];
    const float* W2    = (const float*)d_in[8];
    const float* b2    = (const float*)d_in[9];

    const int E = in_sizes[3];             // bg
    const int D = in_sizes[2] / E;         // Wg = D*E
    const int T = in_sizes[0] / D;         // x  = T*D
    const int H = in_sizes[7] / E;         // b1 = E*H
    float* out = (float*)d_out;

    // ---- workspace layout (element-typed pointers, 16B aligned throughout)
    char* wsb = (char*)d_ws;
    int*   count   = (int*)wsb;                    // [E]    @ 0
    int*   fill    = count + 32;                   // [E]    @ 128B
    int*   offsets = fill + 32;                    // [E+1]  @ 256B
    int*   topk_e  = offsets + 32;                 // [2T]   @ 384B
    float* topk_g  = (float*)(topk_e + 2 * T);     // [2T]
    int*   rows    = (int*)(topk_g + 2 * T);       // [2T]
    float* rgate   = (float*)(rows + 2 * T);       // [2T]
    float* hbuf    = (float*)(rgate + 2 * T);      // [2T x Hc]

    size_t fixed_bytes = (char*)hbuf - wsb;
    size_t avail_elems = (ws_size > fixed_bytes) ? (ws_size - fixed_bytes) / sizeof(float) : 0;
    int Hc = 64;
    for (int c = H; c >= 64; c >>= 1) {
        if ((H % c) == 0 && (size_t)2 * T * (size_t)c <= avail_elems) { Hc = c; break; }
    }

    hipMemsetAsync(wsb, 0, 512, stream);                                  // count/fill/offsets
    hipMemsetAsync(d_out, 0, (size_t)out_size * sizeof(float), stream);   // out accumulates

    if (E == 8) {
        router_kernel<8><<<T, 64, 0, stream>>>(x, noise, Wg, bg, Wn, bn, T, D,
                                               count, topk_e, topk_g);
    } else if (E == 16) {
        router_kernel<16><<<T, 64, 0, stream>>>(x, noise, Wg, bg, Wn, bn, T, D,
                                                count, topk_e, topk_g);
    } else {
        router_kernel<4><<<T, 64, 0, stream>>>(x, noise, Wg, bg, Wn, bn, T, D,
                                               count, topk_e, topk_g);
    }
    scan_kernel<<<1, 64, 0, stream>>>(count, offsets, E);
    scatter_kernel<<<(T + 255) / 256, 256, 0, stream>>>(topk_e, topk_g, offsets, fill,
                                                        rows, rgate, T);

    int nTilesM = (T + 63) / 64;  // worst case: all tokens on one expert
    for (int hc0 = 0; hc0 < H; hc0 += Hc) {
        dim3 g1(Hc / 64, nTilesM, E);
        gemm1_kernel<<<g1, 256, 0, stream>>>(x, W1, b1, count, offsets, rows,
                                             hbuf, D, H, Hc, hc0);
        dim3 g2(D / 64, nTilesM, E);
        gemm2_kernel<<<g2, 256, 0, stream>>>(hbuf, W2, b2, count, offsets, rows, rgate,
                                             out, D, H, Hc, hc0, hc0 == 0 ? 1 : 0);
    }
}

// Round 2
// 1747.767 us; speedup vs baseline: 2.4214x; 2.4214x over previous
//
#include <hip/hip_runtime.h>
#include <math.h>

#define TOPK 2

using bf16x8 = __attribute__((ext_vector_type(8))) short;
using f32x4  = __attribute__((ext_vector_type(4))) float;

__device__ __forceinline__ unsigned short f2bf(float f) {
    unsigned int u = __float_as_uint(f);
    u += 0x7fffu + ((u >> 16) & 1u);          // round-to-nearest-even
    return (unsigned short)(u >> 16);
}
__device__ __forceinline__ float bf2f(unsigned short s) {
    return __uint_as_float(((unsigned int)s) << 16);
}

__device__ __forceinline__ void async_copy16(const void* g, void* l) {
    __builtin_amdgcn_global_load_lds(
        (const __attribute__((address_space(1))) unsigned int*)g,
        (__attribute__((address_space(3))) unsigned int*)l, 16, 0, 0);
}

// ---------------------------------------------------------------- router ---
template<int E>
__global__ __launch_bounds__(64) void router_kernel(
    const float* __restrict__ x, const float* __restrict__ noise,
    const float* __restrict__ Wg, const float* __restrict__ bg,
    const float* __restrict__ Wn, const float* __restrict__ bn,
    int T, int D,
    int* __restrict__ count, int* __restrict__ topk_e, float* __restrict__ topk_g)
{
    int t = blockIdx.x;
    int lane = threadIdx.x;
    float ag[E], an[E];
#pragma unroll
    for (int e = 0; e < E; ++e) { ag[e] = 0.f; an[e] = 0.f; }
    const float* xrow = x + (size_t)t * D;
    for (int d = lane; d < D; d += 64) {
        float xv = xrow[d];
        const float* wgr = Wg + (size_t)d * E;
        const float* wnr = Wn + (size_t)d * E;
#pragma unroll
        for (int e = 0; e < E; ++e) {
            ag[e] = fmaf(xv, wgr[e], ag[e]);
            an[e] = fmaf(xv, wnr[e], an[e]);
        }
    }
#pragma unroll
    for (int e = 0; e < E; ++e) {
#pragma unroll
        for (int off = 32; off; off >>= 1) {
            ag[e] += __shfl_xor(ag[e], off, 64);
            an[e] += __shfl_xor(an[e], off, 64);
        }
    }
    if (lane == 0) {
        float noisy[E];
#pragma unroll
        for (int e = 0; e < E; ++e) {
            float lg = ag[e] + bg[e];
            float nl = an[e] + bn[e];
            float sp = fmaxf(nl, 0.f) + log1pf(expf(-fabsf(nl)));
            noisy[e] = lg + noise[(size_t)t * E + e] * sp;
        }
        int e0 = 0; float v0 = noisy[0];
#pragma unroll
        for (int e = 1; e < E; ++e) if (noisy[e] > v0) { v0 = noisy[e]; e0 = e; }
        int e1 = -1; float v1 = -INFINITY;
#pragma unroll
        for (int e = 0; e < E; ++e) if (e != e0 && noisy[e] > v1) { v1 = noisy[e]; e1 = e; }
        float d1 = expf(v1 - v0);
        float g0 = 1.f / (1.f + d1);
        float g1 = d1 / (1.f + d1);
        topk_e[2 * t] = e0; topk_e[2 * t + 1] = e1;
        topk_g[2 * t] = g0; topk_g[2 * t + 1] = g1;
        atomicAdd(&count[e0], 1);
        atomicAdd(&count[e1], 1);
    }
}

// ------------------------------------------------------------------ scan ---
__global__ void scan_kernel(const int* __restrict__ count, int* __restrict__ offsets, int E)
{
    if (threadIdx.x == 0 && blockIdx.x == 0) {
        int acc = 0;
        for (int e = 0; e < E; ++e) { offsets[e] = acc; acc += count[e]; }
        offsets[E] = acc;
    }
}

// --------------------------------------------------------------- scatter ---
__global__ void scatter_kernel(
    const int* __restrict__ topk_e, const float* __restrict__ topk_g,
    const int* __restrict__ offsets, int* __restrict__ fill,
    int* __restrict__ rows, float* __restrict__ rgate, int T)
{
    int t = blockIdx.x * blockDim.x + threadIdx.x;
    if (t >= T) return;
#pragma unroll
    for (int k = 0; k < TOPK; ++k) {
        int e = topk_e[2 * t + k];
        int slot = atomicAdd(&fill[e], 1);
        int p = offsets[e] + slot;
        rows[p] = t;
        rgate[p] = topk_g[2 * t + k];
    }
}

// --------------------------------------------------------------- split x ---
__global__ void split_x_kernel(const float* __restrict__ x,
                               unsigned short* __restrict__ xh,
                               unsigned short* __restrict__ xl, size_t n4)
{
    size_t i = (size_t)blockIdx.x * blockDim.x + threadIdx.x;
    if (i >= n4) return;
    float4 v = ((const float4*)x)[i];
    ushort4 h, l;
    h.x = f2bf(v.x); l.x = f2bf(v.x - bf2f(h.x));
    h.y = f2bf(v.y); l.y = f2bf(v.y - bf2f(h.y));
    h.z = f2bf(v.z); l.z = f2bf(v.z - bf2f(h.z));
    h.w = f2bf(v.w); l.w = f2bf(v.w - bf2f(h.w));
    ((ushort4*)xh)[i] = h;
    ((ushort4*)xl)[i] = l;
}

// --------------------------------------------- transpose + hi/lo split  ---
// dst[e][n][k] = src[e][srow0+k][scol0+n], split into bf16 hi/lo planes.
__global__ __launch_bounds__(256) void transpose_split_kernel(
    const float* __restrict__ src, size_t sE, int srow0, int ld_s, int scol0,
    unsigned short* __restrict__ dh, unsigned short* __restrict__ dl,
    size_t dE, int ld_d)
{
    const int e  = blockIdx.z;
    const int n0 = blockIdx.x * 32;
    const int k0 = blockIdx.y * 32;
    const int tx = threadIdx.x & 31;
    const int ty = threadIdx.x >> 5;      // 0..7
    __shared__ float tile[32][33];
    const float* s = src + (size_t)e * sE;
#pragma unroll
    for (int p = 0; p < 4; ++p) {
        int k = k0 + ty + 8 * p;
        tile[ty + 8 * p][tx] = s[(size_t)(srow0 + k) * ld_s + scol0 + n0 + tx];
    }
    __syncthreads();
    unsigned short* oh = dh + (size_t)e * dE;
    unsigned short* ol = dl + (size_t)e * dE;
#pragma unroll
    for (int p = 0; p < 4; ++p) {
        int n = n0 + ty + 8 * p;
        float v = tile[tx][ty + 8 * p];
        unsigned short h = f2bf(v);
        unsigned short l = f2bf(v - bf2f(h));
        size_t o = (size_t)n * ld_d + k0 + tx;
        oh[o] = h; ol[o] = l;
    }
}

// -------------------------------------------------------- grouped GEMM ----
// MODE 1: hbuf = relu(gather(x) @ W1c + b1), split-stored as bf16 hi/lo.
// MODE 2: out[token] += gate * (hbuf @ W2c + b2), f32 atomics.
// 128x128 tile, BK=32, 4 waves (2x2), 4x4 16x16x32-MFMA frags per wave.
// 3-term split accumulation: hi*hi + hi*lo + lo*hi.
template<int MODE>
__global__ __launch_bounds__(256, 2) void moe_gemm(
    const short* __restrict__ Agh, const short* __restrict__ Agl,
    const short* __restrict__ Bgh, const short* __restrict__ Bgl,
    size_t Bes,
    const float* __restrict__ bias,
    const int* __restrict__ count, const int* __restrict__ offsets,
    const int* __restrict__ rows, const float* __restrict__ rgate,
    unsigned short* __restrict__ Oh, unsigned short* __restrict__ Ol,
    float* __restrict__ out,
    int lda, int K, int Hc, int H, int D, int hc0, int addb2)
{
    const int e   = blockIdx.z;
    const int cnt = count[e];
    const int m0  = blockIdx.y * 128;
    if (m0 >= cnt) return;
    const int base = offsets[e];
    const int n0   = blockIdx.x * 128;

    const int tid  = threadIdx.x;
    const int wid  = tid >> 6;
    const int lane = tid & 63;
    const int wm   = wid >> 1;
    const int wn   = wid & 1;

    __shared__ __align__(16) short sAh[128 * 32];
    __shared__ __align__(16) short sAl[128 * 32];
    __shared__ __align__(16) short sBh[128 * 32];
    __shared__ __align__(16) short sBl[128 * 32];

    // staging: thread covers LDS rows r2 and r2+64, 16B chunk (tid&3).
    // Source column chunk is inverse-XOR-swizzled so linear LDS writes land
    // swizzled; frag reads apply the same XOR -> bank-conflict-free.
    const int r2 = tid >> 2;
    const int cs = (tid & 3) ^ ((r2 >> 1) & 3);

    int mA0 = m0 + r2;      if (mA0 >= cnt) mA0 = cnt - 1;
    int mA1 = m0 + 64 + r2; if (mA1 >= cnt) mA1 = cnt - 1;
    size_t ar0, ar1;
    if (MODE == 1) { ar0 = (size_t)rows[base + mA0]; ar1 = (size_t)rows[base + mA1]; }
    else           { ar0 = (size_t)(base + mA0);     ar1 = (size_t)(base + mA1); }

    const short* pAh0 = Agh + ar0 * lda + cs * 8;
    const short* pAh1 = Agh + ar1 * lda + cs * 8;
    const short* pAl0 = Agl + ar0 * lda + cs * 8;
    const short* pAl1 = Agl + ar1 * lda + cs * 8;

    const size_t be = (size_t)e * Bes;
    const short* pBh0 = Bgh + be + (size_t)(n0 + r2) * K + cs * 8;
    const short* pBh1 = Bgh + be + (size_t)(n0 + 64 + r2) * K + cs * 8;
    const short* pBl0 = Bgl + be + (size_t)(n0 + r2) * K + cs * 8;
    const short* pBl1 = Bgl + be + (size_t)(n0 + 64 + r2) * K + cs * 8;

    const int lm = lane & 15;
    const int kq = lane >> 4;

    f32x4 acc[4][4];
#pragma unroll
    for (int i = 0; i < 4; ++i)
#pragma unroll
        for (int j = 0; j < 4; ++j)
            acc[i][j] = (f32x4){0.f, 0.f, 0.f, 0.f};

    int offA[4], offB[4];
#pragma unroll
    for (int f = 0; f < 4; ++f) {
        int ra = wm * 64 + f * 16 + lm;
        offA[f] = ra * 32 + (kq ^ ((ra >> 1) & 3)) * 8;
        int rb = wn * 64 + f * 16 + lm;
        offB[f] = rb * 32 + (kq ^ ((rb >> 1) & 3)) * 8;
    }

    for (int k0 = 0; k0 < K; k0 += 32) {
        async_copy16(pAh0 + k0, sAh + tid * 8);
        async_copy16(pAh1 + k0, sAh + (256 + tid) * 8);
        async_copy16(pAl0 + k0, sAl + tid * 8);
        async_copy16(pAl1 + k0, sAl + (256 + tid) * 8);
        async_copy16(pBh0 + k0, sBh + tid * 8);
        async_copy16(pBh1 + k0, sBh + (256 + tid) * 8);
        async_copy16(pBl0 + k0, sBl + tid * 8);
        async_copy16(pBl1 + k0, sBl + (256 + tid) * 8);
        __syncthreads();

        bf16x8 ah[4], al[4], bh[4], bl[4];
#pragma unroll
        for (int f = 0; f < 4; ++f) {
            ah[f] = *(const bf16x8*)(sAh + offA[f]);
            al[f] = *(const bf16x8*)(sAl + offA[f]);
            bh[f] = *(const bf16x8*)(sBh + offB[f]);
            bl[f] = *(const bf16x8*)(sBl + offB[f]);
        }
#pragma unroll
        for (int i = 0; i < 4; ++i)
#pragma unroll
            for (int j = 0; j < 4; ++j) {
                acc[i][j] = __builtin_amdgcn_mfma_f32_16x16x32_bf16(ah[i], bh[j], acc[i][j], 0, 0, 0);
                acc[i][j] = __builtin_amdgcn_mfma_f32_16x16x32_bf16(ah[i], bl[j], acc[i][j], 0, 0, 0);
                acc[i][j] = __builtin_amdgcn_mfma_f32_16x16x32_bf16(al[i], bh[j], acc[i][j], 0, 0, 0);
            }
        __syncthreads();
    }

    if (MODE == 1) {
#pragma unroll
        for (int j = 0; j < 4; ++j) {
            const int nc = n0 + wn * 64 + j * 16 + lm;
            const float bv = bias[(size_t)e * H + hc0 + nc];
#pragma unroll
            for (int i = 0; i < 4; ++i) {
#pragma unroll
                for (int r = 0; r < 4; ++r) {
                    const int m = m0 + wm * 64 + i * 16 + kq * 4 + r;
                    if (m < cnt) {
                        float v = fmaxf(acc[i][j][r] + bv, 0.f);
                        unsigned short h = f2bf(v);
                        unsigned short l = f2bf(v - bf2f(h));
                        size_t o = (size_t)(base + m) * Hc + nc;
                        Oh[o] = h; Ol[o] = l;
                    }
                }
            }
        }
    } else {
#pragma unroll
        for (int i = 0; i < 4; ++i) {
#pragma unroll
            for (int r = 0; r < 4; ++r) {
                const int m = m0 + wm * 64 + i * 16 + kq * 4 + r;
                if (m < cnt) {
                    const int t = rows[base + m];
                    const float g = rgate[base + m];
                    float* orow = out + (size_t)t * D;
#pragma unroll
                    for (int j = 0; j < 4; ++j) {
                        const int nc = n0 + wn * 64 + j * 16 + lm;
                        float v = acc[i][j][r];
                        if (addb2) v += bias[(size_t)e * D + nc];
                        atomicAdd(orow + nc, g * v);
                    }
                }
            }
        }
    }
}

// ------------------------------------------------------------------ host ---
extern "C" void kernel_launch(void* const* d_in, const int* in_sizes, int n_in,
                              void* d_out, int out_size, void* d_ws, size_t ws_size,
                              hipStream_t stream)
{
    const float* x     = (const float*)d_in[0];
    const float* noise = (const float*)d_in[1];
    const float* Wg    = (const float*)d_in[2];
    const float* bg    = (const float*)d_in[3];
    const float* Wn    = (const float*)d_in[4];
    const float* bn    = (const float*)d_in[5];
    const float* W1    = (const float*)d_in[6];
    const float* b1    = (const float*)d_in[7];
    const float* W2    = (const float*)d_in[8];
    const float* b2    = (const float*)d_in[9];

    const int E = in_sizes[3];
    const int D = in_sizes[2] / E;
    const int T = in_sizes[0] / D;
    const int H = in_sizes[7] / E;
    const int T2 = 2 * T;
    float* out = (float*)d_out;

    char* p = (char*)d_ws;
    auto alloc = [&](size_t bytes) -> char* {
        char* r = p; p += (bytes + 255) & ~(size_t)255; return r;
    };

    int*   count   = (int*)alloc(256);
    int*   fill    = (int*)alloc(256);
    int*   offsets = (int*)alloc(256);
    int*   topk_e  = (int*)alloc((size_t)T2 * 4);
    float* topk_g  = (float*)alloc((size_t)T2 * 4);
    int*   rows    = (int*)alloc((size_t)T2 * 4);
    float* rgate   = (float*)alloc((size_t)T2 * 4);
    unsigned short* xh = (unsigned short*)alloc((size_t)T * D * 2);
    unsigned short* xl = (unsigned short*)alloc((size_t)T * D * 2);

    const size_t fixed = (size_t)(p - (char*)d_ws);
    auto pad = [](size_t b) { return (b + 255) & ~(size_t)255; };
    int Hc = 128;
    for (int c = H; c >= 128; c >>= 1) {
        if (H % c) continue;
        size_t need = fixed
            + 2 * pad((size_t)E * c * D * 2)   // W1 planes
            + 2 * pad((size_t)E * D * c * 2)   // W2 planes
            + 2 * pad((size_t)T2 * c * 2);     // hbuf planes
        if (need <= ws_size) { Hc = c; break; }
    }
    unsigned short* w1h = (unsigned short*)alloc((size_t)E * Hc * D * 2);
    unsigned short* w1l = (unsigned short*)alloc((size_t)E * Hc * D * 2);
    unsigned short* w2h = (unsigned short*)alloc((size_t)E * D * Hc * 2);
    unsigned short* w2l = (unsigned short*)alloc((size_t)E * D * Hc * 2);
    unsigned short* hbh = (unsigned short*)alloc((size_t)T2 * Hc * 2);
    unsigned short* hbl = (unsigned short*)alloc((size_t)T2 * Hc * 2);

    hipMemsetAsync(d_ws, 0, 768, stream);
    hipMemsetAsync(d_out, 0, (size_t)out_size * 4, stream);

    if (E == 8) {
        router_kernel<8><<<T, 64, 0, stream>>>(x, noise, Wg, bg, Wn, bn, T, D,
                                               count, topk_e, topk_g);
    } else if (E == 16) {
        router_kernel<16><<<T, 64, 0, stream>>>(x, noise, Wg, bg, Wn, bn, T, D,
                                                count, topk_e, topk_g);
    } else {
        router_kernel<4><<<T, 64, 0, stream>>>(x, noise, Wg, bg, Wn, bn, T, D,
                                               count, topk_e, topk_g);
    }
    scan_kernel<<<1, 64, 0, stream>>>(count, offsets, E);
    scatter_kernel<<<(T + 255) / 256, 256, 0, stream>>>(topk_e, topk_g, offsets, fill,
                                                        rows, rgate, T);
    split_x_kernel<<<((T * D / 4) + 255) / 256, 256, 0, stream>>>(
        x, xh, xl, (size_t)T * D / 4);

    const int nTm = (T + 127) / 128;
    for (int hc0 = 0; hc0 < H; hc0 += Hc) {
        // W1 chunk: [D][hc0:hc0+Hc] -> [Hc][D]
        transpose_split_kernel<<<dim3(Hc / 32, D / 32, E), 256, 0, stream>>>(
            W1, (size_t)D * H, 0, H, hc0, w1h, w1l, (size_t)Hc * D, D);
        // W2 chunk: [hc0:hc0+Hc][D] -> [D][Hc]
        transpose_split_kernel<<<dim3(D / 32, Hc / 32, E), 256, 0, stream>>>(
            W2, (size_t)H * D, hc0, D, 0, w2h, w2l, (size_t)D * Hc, Hc);

        moe_gemm<1><<<dim3(Hc / 128, nTm, E), 256, 0, stream>>>(
            (const short*)xh, (const short*)xl, (const short*)w1h, (const short*)w1l,
            (size_t)Hc * D, b1, count, offsets, rows, rgate,
            hbh, hbl, nullptr, D, D, Hc, H, D, hc0, 0);

        moe_gemm<2><<<dim3(D / 128, nTm, E), 256, 0, stream>>>(
            (const short*)hbh, (const short*)hbl, (const short*)w2h, (const short*)w2l,
            (size_t)D * Hc, b2, count, offsets, rows, rgate,
            nullptr, nullptr, out, Hc, Hc, Hc, H, D, hc0, hc0 == 0 ? 1 : 0);
    }
}